// Round 4
// baseline (246.659 us; speedup 1.0000x reference)
//
#include <hip/hip_runtime.h>
#include <math.h>

#define T_LEN 2048
#define B_SZ 4
#define D_MODEL 1024
#define NH 16
#define HD 64
#define BH_TOT (B_SZ*NH)

typedef __attribute__((ext_vector_type(8))) short bf16x8;
typedef __attribute__((ext_vector_type(4))) float f32x4;
typedef __attribute__((ext_vector_type(8))) unsigned short u16x8;

union U8 { unsigned int u[4]; bf16x8 v; };

static __device__ __forceinline__ unsigned short f2bf(float f) {
  unsigned int x = __float_as_uint(f);
  x += 0x7fffu + ((x >> 16) & 1u);
  return (unsigned short)(x >> 16);
}
static __device__ __forceinline__ float bf2f(unsigned short u) {
  return __uint_as_float(((unsigned int)u) << 16);
}
// async global->LDS DMA, 16B per lane; LDS dest = wave-uniform base + lane*16
static __device__ __forceinline__ void gload16(const void* g, void* l) {
  __builtin_amdgcn_global_load_lds((const __attribute__((address_space(1))) void*)g,
                                   (__attribute__((address_space(3))) void*)l, 16, 0, 0);
}

// ---------------- fp32 -> bf16 convert (8 elems/thread) ----------------
__global__ __launch_bounds__(256) void cvt_bf16_kernel(const float* __restrict__ src,
                                                       unsigned short* __restrict__ dst,
                                                       int n8) {
  const int i = blockIdx.x * 256 + threadIdx.x;
  if (i >= n8) return;
  const float4 a = ((const float4*)src)[i * 2];
  const float4 b = ((const float4*)src)[i * 2 + 1];
  u16x8 o;
  o[0] = f2bf(a.x); o[1] = f2bf(a.y); o[2] = f2bf(a.z); o[3] = f2bf(a.w);
  o[4] = f2bf(b.x); o[5] = f2bf(b.y); o[6] = f2bf(b.z); o[7] = f2bf(b.w);
  ((u16x8*)dst)[i] = o;
}

// ---------------- bf16 MFMA GEMM: C = A(MxK) * W(NxK)^T + bias ----------------
// 128x128 tile, BK=64, 4 waves (2x2). global_load_lds staging (m97 structure):
// linear LDS dest, pre-swizzled global source, swizzled ds_read.
__global__ __launch_bounds__(256, 2) void gemm_mfma_kernel(
    const unsigned short* __restrict__ A, const unsigned short* __restrict__ W,
    const float* __restrict__ bias, float* __restrict__ C,
    int M, int N, int K, int mode,
    unsigned short* __restrict__ qd, unsigned short* __restrict__ kd,
    unsigned short* __restrict__ vd)
{
  __shared__ unsigned short As[128 * 64];   // [row][64 bf16]
  __shared__ unsigned short Bs[128 * 64];
  const int tid = threadIdx.x;
  const int l = tid & 63, w = tid >> 6;
  const int lq = l & 15, lg = l >> 4;
  const int wm = w >> 1, wn = w & 1;
  const int n0 = blockIdx.x * 128, m0 = blockIdx.y * 128;

  // per-lane pre-swizzled source column (bytes); row-within-8-group = l>>3
  const int lrow = l >> 3;
  const int lcolb = ((l & 7) << 4) ^ (lrow << 4);

  f32x4 acc[4][4];
#pragma unroll
  for (int mt = 0; mt < 4; ++mt)
#pragma unroll
    for (int nt = 0; nt < 4; ++nt)
#pragma unroll
      for (int r2 = 0; r2 < 4; ++r2) acc[mt][nt][r2] = 0.f;

  for (int k0 = 0; k0 < K; k0 += 64) {
    __syncthreads();                        // prev compute done before overwrite
#pragma unroll
    for (int c = 0; c < 4; ++c) {
      const int r0 = w * 32 + c * 8;
      const int row = r0 + lrow;
      gload16((const char*)A + ((size_t)(m0 + row) * K + k0) * 2 + lcolb,
              (char*)As + r0 * 128);
      gload16((const char*)W + ((size_t)(n0 + row) * K + k0) * 2 + lcolb,
              (char*)Bs + r0 * 128);
    }
    __syncthreads();                        // drains vmcnt -> tiles ready

#pragma unroll
    for (int kc = 0; kc < 2; ++kc) {
      bf16x8 af[4], bfr[4];
#pragma unroll
      for (int mt = 0; mt < 4; ++mt) {
        const int r = wm * 64 + mt * 16 + lq;
        af[mt] = *(const bf16x8*)((const char*)As + r * 128 +
                                  ((kc * 64 + lg * 16) ^ ((r & 7) << 4)));
      }
#pragma unroll
      for (int nt = 0; nt < 4; ++nt) {
        const int r = wn * 64 + nt * 16 + lq;
        bfr[nt] = *(const bf16x8*)((const char*)Bs + r * 128 +
                                   ((kc * 64 + lg * 16) ^ ((r & 7) << 4)));
      }
#pragma unroll
      for (int mt = 0; mt < 4; ++mt)
#pragma unroll
        for (int nt = 0; nt < 4; ++nt)
          acc[mt][nt] = __builtin_amdgcn_mfma_f32_16x16x32_bf16(af[mt], bfr[nt], acc[mt][nt], 0, 0, 0);
    }
  }

  if (mode == 0) {
#pragma unroll
    for (int nt = 0; nt < 4; ++nt) {
      const int n = n0 + wn * 64 + nt * 16 + lq;
      const float bv = bias[n];
#pragma unroll
      for (int mt = 0; mt < 4; ++mt)
#pragma unroll
        for (int r2 = 0; r2 < 4; ++r2) {
          const int m = m0 + wm * 64 + mt * 16 + lg * 4 + r2;
          C[(size_t)m * N + n] = acc[mt][nt][r2] + bv;
        }
    }
  } else {
#pragma unroll
    for (int nt = 0; nt < 4; ++nt) {
      const int n = n0 + wn * 64 + nt * 16 + lq;
      const float bv = bias[n];
      const int which = n >> 10;
      const int h = (n >> 6) & (NH - 1);
      const int hd = n & 63;
      unsigned short* dst = (which == 0) ? qd : (which == 1) ? kd : vd;
#pragma unroll
      for (int mt = 0; mt < 4; ++mt)
#pragma unroll
        for (int r2 = 0; r2 < 4; ++r2) {
          const int m = m0 + wm * 64 + mt * 16 + lg * 4 + r2;
          const int t = m >> 2, b = m & 3;
          dst[((size_t)(b * NH + h) * T_LEN + t) * HD + hd] = f2bf(acc[mt][nt][r2] + bv);
        }
    }
  }
}

// ---------------- RoPE in place; q pre-scaled by log2(e)/8 (exp2-domain softmax) ----------------
__global__ void rope_bf16_kernel(unsigned short* __restrict__ qb, unsigned short* __restrict__ kb)
{
  const int idx = blockIdx.x * blockDim.x + threadIdx.x;
  const int i  = idx & 31;
  const int t  = (idx >> 5) & (T_LEN - 1);
  const int bh = idx >> 16;
  const float inv_freq = powf(10000.f, -(float)i / 32.f);
  float s, c;
  sincosf((float)t * inv_freq, &s, &c);
  const size_t base = ((size_t)bh * T_LEN + t) * HD;
  const float QS = 0.18033688011112042f;   // (1/8) * log2(e)
  const float q1 = bf2f(qb[base + i]), q2 = bf2f(qb[base + i + 32]);
  qb[base + i]      = f2bf((q1 * c - q2 * s) * QS);
  qb[base + i + 32] = f2bf((q2 * c + q1 * s) * QS);
  const float k1 = bf2f(kb[base + i]), k2 = bf2f(kb[base + i + 32]);
  kb[base + i]      = f2bf(k1 * c - k2 * s);
  kb[base + i + 32] = f2bf(k2 * c + k1 * s);
}

// ---------------- V transpose: bf16 [bh][t][64] -> bf16 [bh][64][2048] ----------------
__global__ __launch_bounds__(256) void vtrans_kernel(const unsigned short* __restrict__ v,
                                                     unsigned short* __restrict__ vt)
{
  __shared__ unsigned short Ls[64][65];
  const int tid = threadIdx.x;
  const int bh = blockIdx.x, t0 = blockIdx.y * 64;
  {
    const int r = tid >> 2, c0 = (tid & 3) * 16;
    const unsigned short* src = v + ((size_t)bh * T_LEN + t0 + r) * HD + c0;
    u16x8 f0 = *(const u16x8*)src;
    u16x8 f1 = *(const u16x8*)(src + 8);
#pragma unroll
    for (int e = 0; e < 8; ++e) { Ls[r][c0 + e] = f0[e]; Ls[r][c0 + 8 + e] = f1[e]; }
  }
  __syncthreads();
  {
    const int d = tid >> 2, u0 = (tid & 3) * 16;
    u16x8 o0, o1;
#pragma unroll
    for (int e = 0; e < 8; ++e) { o0[e] = Ls[u0 + e][d]; o1[e] = Ls[u0 + 8 + e][d]; }
    unsigned short* dst = vt + ((size_t)bh * HD + d) * T_LEN + t0 + u0;
    *(u16x8*)dst = o0;
    *(u16x8*)(dst + 8) = o1;
  }
}

// ---------------- bf16 MFMA flash attention ----------------
// Block: (bh, 128 q rows), 4 waves, wave w owns 32 q rows (2 frag sets qh=0,1).
// LDS double-buffered K/V tiles of 64 keys; global_load_lds staged one tile ahead.
__global__ __launch_bounds__(256) void attn_mfma_kernel(
    const unsigned short* __restrict__ Qb,   // [bh][t][64] bf16, pre-scaled log2e/8
    const unsigned short* __restrict__ Kb,   // [bh][t][64] bf16
    const unsigned short* __restrict__ Vt,   // [bh][64][2048] bf16 (transposed)
    unsigned short* __restrict__ ctx)        // (T, B, D) bf16
{
  __shared__ unsigned short Ks[2][64 * 64];
  __shared__ unsigned short Vs[2][64 * 64];
  const int tid = threadIdx.x;
  const int l = tid & 63;
  const int w = tid >> 6;
  const int lq = l & 15, lg = l >> 4;
  const int bh = blockIdx.x;
  const int qc = (T_LEN / 128 - 1) - blockIdx.y;   // tail-first: longest blocks dispatch first
  const int b = bh >> 4, h = bh & 15;
  const size_t tb = (size_t)bh * T_LEN;

  const int q0 = qc * 128 + w * 32;                // wave's 32 q rows
  bf16x8 qf[2][2];
#pragma unroll
  for (int qh = 0; qh < 2; ++qh) {
    const unsigned short* qr = Qb + (tb + q0 + qh * 16 + lq) * HD + lg * 8;
    qf[qh][0] = *(const bf16x8*)qr;
    qf[qh][1] = *(const bf16x8*)(qr + 32);
  }

  f32x4 acc[2][4];
#pragma unroll
  for (int qh = 0; qh < 2; ++qh)
#pragma unroll
    for (int dt = 0; dt < 4; ++dt)
#pragma unroll
      for (int r2 = 0; r2 < 4; ++r2) acc[qh][dt][r2] = 0.f;
  float mrun[2] = {-1e30f, -1e30f}, lsum[2] = {0.f, 0.f};

  // staging geometry: wave w covers rows [w*16, w*16+16) in 2 issues of 8 rows
  const int lrow = l >> 3;
  const int lcolb = ((l & 7) << 4) ^ (lrow << 4);  // pre-swizzled source col
  const int last = 2 * qc + 1;

  // prologue: stage tile 0 into buffer 0
#pragma unroll
  for (int c = 0; c < 2; ++c) {
    const int r0 = w * 16 + c * 8;
    const int row = r0 + lrow;
    gload16((const char*)Kb + ((tb + 0 + row) * HD) * 2 + lcolb, (char*)Ks[0] + r0 * 128);
    gload16((const char*)Vt + (((size_t)bh * HD + row) * T_LEN + 0) * 2 + lcolb,
            (char*)Vs[0] + r0 * 128);
  }
  __syncthreads();                                 // vmcnt drained, tile 0 ready

  for (int kbi = 0; kbi <= last; ++kbi) {
    const int s0 = kbi * 64;
    const int cur = kbi & 1;

    // issue next tile's DMA now; it lands before the barrier at loop end
    if (kbi < last) {
      const int sn = s0 + 64;
#pragma unroll
      for (int c = 0; c < 2; ++c) {
        const int r0 = w * 16 + c * 8;
        const int row = r0 + lrow;
        gload16((const char*)Kb + ((tb + sn + row) * HD) * 2 + lcolb,
                (char*)Ks[cur ^ 1] + r0 * 128);
        gload16((const char*)Vt + (((size_t)bh * HD + row) * T_LEN + sn) * 2 + lcolb,
                (char*)Vs[cur ^ 1] + r0 * 128);
      }
    }

    const int dmax = q0 + 31 - s0;
    if (dmax >= 0) {                               // wave has work in this tile
      const int stMax = min(4, (dmax >> 4) + 1);
      const int kcMax = min(2, (dmax >> 5) + 1);
      const bool maskN = (s0 + 63 > q0);

      f32x4 sv[2][4];
#pragma unroll
      for (int qh = 0; qh < 2; ++qh)
#pragma unroll
        for (int st = 0; st < 4; ++st)
#pragma unroll
          for (int r2 = 0; r2 < 4; ++r2) sv[qh][st][r2] = -1e30f;

#pragma unroll
      for (int st = 0; st < 4; ++st) if (st < stMax) {
        const int r = st * 16 + lq;
        const int x = (r & 7) << 4;
        bf16x8 ka0 = *(const bf16x8*)((const char*)Ks[cur] + r * 128 + ((lg * 16) ^ x));
        bf16x8 ka1 = *(const bf16x8*)((const char*)Ks[cur] + r * 128 + (((lg + 4) * 16) ^ x));
#pragma unroll
        for (int qh = 0; qh < 2; ++qh) {
          f32x4 z;
#pragma unroll
          for (int r2 = 0; r2 < 4; ++r2) z[r2] = 0.f;
          z = __builtin_amdgcn_mfma_f32_16x16x32_bf16(ka1, qf[qh][1], z, 0, 0, 0);
          z = __builtin_amdgcn_mfma_f32_16x16x32_bf16(ka0, qf[qh][0], z, 0, 0, 0);
          sv[qh][st] = z;
        }
      }

      if (maskN) {
#pragma unroll
        for (int qh = 0; qh < 2; ++qh) {
          const int qg = q0 + qh * 16 + lq;
#pragma unroll
          for (int st = 0; st < 4; ++st)
#pragma unroll
            for (int r2 = 0; r2 < 4; ++r2) {
              const int sg = s0 + st * 16 + lg * 4 + r2;
              if (sg > qg) sv[qh][st][r2] = -1e30f;
            }
        }
      }

      unsigned int lo[2][4], hi[2][4];
#pragma unroll
      for (int qh = 0; qh < 2; ++qh) {
        float tmax = -1e30f;
#pragma unroll
        for (int st = 0; st < 4; ++st)
#pragma unroll
          for (int r2 = 0; r2 < 4; ++r2) tmax = fmaxf(tmax, sv[qh][st][r2]);
        tmax = fmaxf(tmax, __shfl_xor(tmax, 16));
        tmax = fmaxf(tmax, __shfl_xor(tmax, 32));
        const float mnew = fmaxf(mrun[qh], tmax);
        const float alpha = exp2f(mrun[qh] - mnew);
        float p[4][4];
        float ps = 0.f;
#pragma unroll
        for (int st = 0; st < 4; ++st)
#pragma unroll
          for (int r2 = 0; r2 < 4; ++r2) {
            p[st][r2] = exp2f(sv[qh][st][r2] - mnew);
            ps += p[st][r2];
          }
        ps += __shfl_xor(ps, 16);
        ps += __shfl_xor(ps, 32);
        lsum[qh] = lsum[qh] * alpha + ps;
        mrun[qh] = mnew;

        float a4[4];
#pragma unroll
        for (int r2 = 0; r2 < 4; ++r2) a4[r2] = __shfl(alpha, lg * 4 + r2);
#pragma unroll
        for (int dt = 0; dt < 4; ++dt)
#pragma unroll
          for (int r2 = 0; r2 < 4; ++r2) acc[qh][dt][r2] *= a4[r2];

#pragma unroll
        for (int st = 0; st < 4; ++st) {
          asm("v_cvt_pk_bf16_f32 %0, %1, %2" : "=v"(lo[qh][st]) : "v"(p[st][0]), "v"(p[st][1]));
          asm("v_cvt_pk_bf16_f32 %0, %1, %2" : "=v"(hi[qh][st]) : "v"(p[st][2]), "v"(p[st][3]));
        }
      }

      const int srcA = lq + 32 * (lg & 1);
      const bool hiT = ((lg >> 1) & 1) != 0;
#pragma unroll
      for (int kc = 0; kc < 2; ++kc) if (kc < kcMax) {
        U8 pa[2];
#pragma unroll
        for (int qh = 0; qh < 2; ++qh) {
          {
            unsigned int ta = __shfl(lo[qh][2*kc], srcA),      tb2 = __shfl(lo[qh][2*kc+1], srcA);
            pa[qh].u[0] = hiT ? tb2 : ta;
          }
          {
            unsigned int ta = __shfl(hi[qh][2*kc], srcA),      tb2 = __shfl(hi[qh][2*kc+1], srcA);
            pa[qh].u[1] = hiT ? tb2 : ta;
          }
          {
            unsigned int ta = __shfl(lo[qh][2*kc], srcA + 16), tb2 = __shfl(lo[qh][2*kc+1], srcA + 16);
            pa[qh].u[2] = hiT ? tb2 : ta;
          }
          {
            unsigned int ta = __shfl(hi[qh][2*kc], srcA + 16), tb2 = __shfl(hi[qh][2*kc+1], srcA + 16);
            pa[qh].u[3] = hiT ? tb2 : ta;
          }
        }
#pragma unroll
        for (int dt = 0; dt < 4; ++dt) {
          const int d = dt * 16 + lq;
          bf16x8 vb = *(const bf16x8*)((const char*)Vs[cur] + d * 128 +
                                       (((4 * kc + lg) * 16) ^ ((d & 7) << 4)));
#pragma unroll
          for (int qh = 0; qh < 2; ++qh)
            acc[qh][dt] = __builtin_amdgcn_mfma_f32_16x16x32_bf16(pa[qh].v, vb, acc[qh][dt], 0, 0, 0);
        }
      }
    }

    __syncthreads();     // all reads of buf[cur] done AND next tile's DMA drained
  }

#pragma unroll
  for (int qh = 0; qh < 2; ++qh) {
    const float linv = 1.f / lsum[qh];
    float l4[4];
#pragma unroll
    for (int r2 = 0; r2 < 4; ++r2) l4[r2] = __shfl(linv, lg * 4 + r2);
#pragma unroll
    for (int dt = 0; dt < 4; ++dt)
#pragma unroll
      for (int r2 = 0; r2 < 4; ++r2) {
        const int qrow = q0 + qh * 16 + lg * 4 + r2;
        ctx[((size_t)qrow * B_SZ + b) * D_MODEL + h * HD + dt * 16 + lq] =
            f2bf(acc[qh][dt][r2] * linv * 0.f + acc[qh][dt][r2] * l4[r2]);
      }
  }
}

extern "C" void kernel_launch(void* const* d_in, const int* in_sizes, int n_in,
                              void* d_out, int out_size, void* d_ws, size_t ws_size,
                              hipStream_t stream) {
  const float* x    = (const float*)d_in[0];
  const float* Wqkv = (const float*)d_in[2];
  const float* bqkv = (const float*)d_in[3];
  const float* Wout = (const float*)d_in[4];
  const float* bout = (const float*)d_in[5];
  float* out = (float*)d_out;

  char* wsb = (char*)d_ws;
  unsigned short* xb    = (unsigned short*)(wsb);
  unsigned short* wqkvb = (unsigned short*)(wsb + (16ull << 20));
  unsigned short* woutb = (unsigned short*)(wsb + (22ull << 20));
  unsigned short* qb    = (unsigned short*)(wsb + (24ull << 20));
  unsigned short* kb    = (unsigned short*)(wsb + (40ull << 20));
  unsigned short* vb    = (unsigned short*)(wsb + (56ull << 20));
  unsigned short* vt    = (unsigned short*)(wsb + (72ull << 20));
  unsigned short* ctxb  = (unsigned short*)(wsb + (88ull << 20));

  cvt_bf16_kernel<<<(T_LEN*B_SZ*D_MODEL/8 + 255)/256, 256, 0, stream>>>(x, xb, T_LEN*B_SZ*D_MODEL/8);
  cvt_bf16_kernel<<<(3*D_MODEL*D_MODEL/8 + 255)/256, 256, 0, stream>>>(Wqkv, wqkvb, 3*D_MODEL*D_MODEL/8);
  cvt_bf16_kernel<<<(D_MODEL*D_MODEL/8 + 255)/256, 256, 0, stream>>>(Wout, woutb, D_MODEL*D_MODEL/8);

  dim3 g1(3 * D_MODEL / 128, (T_LEN * B_SZ) / 128);
  gemm_mfma_kernel<<<g1, 256, 0, stream>>>(xb, wqkvb, bqkv, nullptr,
                                           T_LEN * B_SZ, 3 * D_MODEL, D_MODEL, 1,
                                           qb, kb, vb);
  const int rope_total = BH_TOT * T_LEN * (HD / 2);
  rope_bf16_kernel<<<(rope_total + 255) / 256, 256, 0, stream>>>(qb, kb);

  dim3 gvt(BH_TOT, T_LEN / 64);
  vtrans_kernel<<<gvt, 256, 0, stream>>>(vb, vt);

  dim3 g2(BH_TOT, T_LEN / 128);
  attn_mfma_kernel<<<g2, 256, 0, stream>>>(qb, kb, vt, ctxb);

  dim3 g3(D_MODEL / 128, (T_LEN * B_SZ) / 128);
  gemm_mfma_kernel<<<g3, 256, 0, stream>>>(ctxb, woutb, bout, out,
                                           T_LEN * B_SZ, D_MODEL, D_MODEL, 0,
                                           nullptr, nullptr, nullptr);
}

// Round 5
// 224.807 us; speedup vs baseline: 1.0972x; 1.0972x over previous
//
#include <hip/hip_runtime.h>
#include <math.h>

#define T_LEN 2048
#define B_SZ 4
#define D_MODEL 1024
#define NH 16
#define HD 64
#define BH_TOT (B_SZ*NH)

typedef __attribute__((ext_vector_type(8))) short bf16x8;
typedef __attribute__((ext_vector_type(4))) float f32x4;
typedef __attribute__((ext_vector_type(16))) float f32x16;
typedef __attribute__((ext_vector_type(8))) unsigned short u16x8;
typedef __attribute__((ext_vector_type(4))) unsigned short u16x4;

union U8 { unsigned int u[4]; bf16x8 v; };

static __device__ __forceinline__ unsigned short f2bf(float f) {
  unsigned int x = __float_as_uint(f);
  x += 0x7fffu + ((x >> 16) & 1u);
  return (unsigned short)(x >> 16);
}
static __device__ __forceinline__ float bf2f(unsigned short u) {
  return __uint_as_float(((unsigned int)u) << 16);
}
// async global->LDS DMA, 16B per lane; LDS dest = wave-uniform base + lane*16
static __device__ __forceinline__ void gload16(const void* g, void* l) {
  __builtin_amdgcn_global_load_lds((const __attribute__((address_space(1))) void*)g,
                                   (__attribute__((address_space(3))) void*)l, 16, 0, 0);
}

// ---------------- fp32 -> bf16 convert (8 elems/thread) ----------------
__global__ __launch_bounds__(256) void cvt_bf16_kernel(const float* __restrict__ src,
                                                       unsigned short* __restrict__ dst,
                                                       int n8) {
  const int i = blockIdx.x * 256 + threadIdx.x;
  if (i >= n8) return;
  const float4 a = ((const float4*)src)[i * 2];
  const float4 b = ((const float4*)src)[i * 2 + 1];
  u16x8 o;
  o[0] = f2bf(a.x); o[1] = f2bf(a.y); o[2] = f2bf(a.z); o[3] = f2bf(a.w);
  o[4] = f2bf(b.x); o[5] = f2bf(b.y); o[6] = f2bf(b.z); o[7] = f2bf(b.w);
  ((u16x8*)dst)[i] = o;
}

// ---------------- bf16 MFMA GEMM: C = A(MxK) * W(NxK)^T + bias ----------------
// 128x128 tile, BK=64, 4 waves (2x2). global_load_lds staging (m97 structure).
// mode 0: fp32 C[m*N+n]
// mode 1: bf16 scatter q,k -> [bh][t][hd]; v -> TRANSPOSED [bh][hd][t]
__global__ __launch_bounds__(256, 2) void gemm_mfma_kernel(
    const unsigned short* __restrict__ A, const unsigned short* __restrict__ W,
    const float* __restrict__ bias, float* __restrict__ C,
    int M, int N, int K, int mode,
    unsigned short* __restrict__ qd, unsigned short* __restrict__ kd,
    unsigned short* __restrict__ vtd)
{
  __shared__ unsigned short As[128 * 64];   // [row][64 bf16]
  __shared__ unsigned short Bs[128 * 64];
  const int tid = threadIdx.x;
  const int l = tid & 63, w = tid >> 6;
  const int lq = l & 15, lg = l >> 4;
  const int wm = w >> 1, wn = w & 1;
  const int n0 = blockIdx.x * 128, m0 = blockIdx.y * 128;

  const int lrow = l >> 3;
  const int lcolb = ((l & 7) << 4) ^ (lrow << 4);   // pre-swizzled source col

  f32x4 acc[4][4];
#pragma unroll
  for (int mt = 0; mt < 4; ++mt)
#pragma unroll
    for (int nt = 0; nt < 4; ++nt)
#pragma unroll
      for (int r2 = 0; r2 < 4; ++r2) acc[mt][nt][r2] = 0.f;

  for (int k0 = 0; k0 < K; k0 += 64) {
    __syncthreads();
#pragma unroll
    for (int c = 0; c < 4; ++c) {
      const int r0 = w * 32 + c * 8;
      const int row = r0 + lrow;
      gload16((const char*)A + ((size_t)(m0 + row) * K + k0) * 2 + lcolb,
              (char*)As + r0 * 128);
      gload16((const char*)W + ((size_t)(n0 + row) * K + k0) * 2 + lcolb,
              (char*)Bs + r0 * 128);
    }
    __syncthreads();

#pragma unroll
    for (int kc = 0; kc < 2; ++kc) {
      bf16x8 af[4], bfr[4];
#pragma unroll
      for (int mt = 0; mt < 4; ++mt) {
        const int r = wm * 64 + mt * 16 + lq;
        af[mt] = *(const bf16x8*)((const char*)As + r * 128 +
                                  ((kc * 64 + lg * 16) ^ ((r & 7) << 4)));
      }
#pragma unroll
      for (int nt = 0; nt < 4; ++nt) {
        const int r = wn * 64 + nt * 16 + lq;
        bfr[nt] = *(const bf16x8*)((const char*)Bs + r * 128 +
                                   ((kc * 64 + lg * 16) ^ ((r & 7) << 4)));
      }
#pragma unroll
      for (int mt = 0; mt < 4; ++mt)
#pragma unroll
        for (int nt = 0; nt < 4; ++nt)
          acc[mt][nt] = __builtin_amdgcn_mfma_f32_16x16x32_bf16(af[mt], bfr[nt], acc[mt][nt], 0, 0, 0);
    }
  }

  if (mode == 0) {
#pragma unroll
    for (int nt = 0; nt < 4; ++nt) {
      const int n = n0 + wn * 64 + nt * 16 + lq;
      const float bv = bias[n];
#pragma unroll
      for (int mt = 0; mt < 4; ++mt)
#pragma unroll
        for (int r2 = 0; r2 < 4; ++r2) {
          const int m = m0 + wm * 64 + mt * 16 + lg * 4 + r2;
          C[(size_t)m * N + n] = acc[mt][nt][r2] + bv;
        }
    }
  } else {
#pragma unroll
    for (int nt = 0; nt < 4; ++nt) {
      const int n = n0 + wn * 64 + nt * 16 + lq;
      const float bv = bias[n];
      const int which = n >> 10;
      const int h = (n >> 6) & (NH - 1);
      const int hd = n & 63;
#pragma unroll
      for (int mt = 0; mt < 4; ++mt)
#pragma unroll
        for (int r2 = 0; r2 < 4; ++r2) {
          const int m = m0 + wm * 64 + mt * 16 + lg * 4 + r2;
          const int t = m >> 2, b = m & 3;
          const unsigned short val = f2bf(acc[mt][nt][r2] + bv);
          if (which == 2) {
            vtd[((size_t)(b * NH + h) * HD + hd) * T_LEN + t] = val;   // V transposed
          } else {
            unsigned short* dst = (which == 0) ? qd : kd;
            dst[((size_t)(b * NH + h) * T_LEN + t) * HD + hd] = val;
          }
        }
    }
  }
}

// ---------------- RoPE in place; q pre-scaled by log2(e)/8 (exp2-domain softmax) ----------------
__global__ void rope_bf16_kernel(unsigned short* __restrict__ qb, unsigned short* __restrict__ kb)
{
  const int idx = blockIdx.x * blockDim.x + threadIdx.x;
  const int i  = idx & 31;
  const int t  = (idx >> 5) & (T_LEN - 1);
  const int bh = idx >> 16;
  const float inv_freq = powf(10000.f, -(float)i / 32.f);
  float s, c;
  sincosf((float)t * inv_freq, &s, &c);
  const size_t base = ((size_t)bh * T_LEN + t) * HD;
  const float QS = 0.18033688011112042f;   // (1/8) * log2(e)
  const float q1 = bf2f(qb[base + i]), q2 = bf2f(qb[base + i + 32]);
  qb[base + i]      = f2bf((q1 * c - q2 * s) * QS);
  qb[base + i + 32] = f2bf((q2 * c + q1 * s) * QS);
  const float k1 = bf2f(kb[base + i]), k2 = bf2f(kb[base + i + 32]);
  kb[base + i]      = f2bf(k1 * c - k2 * s);
  kb[base + i + 32] = f2bf(k2 * c + k1 * s);
}

// ---------------- bf16 32x32-MFMA flash attention, fully swapped orientation ----------------
// Block: (bh, 128 q rows), 4 waves, wave w owns 32 q rows. Lane's q = l&31 for
// softmax AND output (ctx^T = mfma(V^T, P^T)) -> per-lane scalar m/l/alpha.
// P^T B-frags built with cvt_pk + v_permlane32_swap (no ds_bpermute).
__global__ __launch_bounds__(256, 3) void attn_mfma_kernel(
    const unsigned short* __restrict__ Qb,   // [bh][t][64] bf16, pre-scaled log2e/8
    const unsigned short* __restrict__ Kb,   // [bh][t][64] bf16
    const unsigned short* __restrict__ Vt,   // [bh][64][2048] bf16 (transposed)
    unsigned short* __restrict__ ctx)        // (T, B, D) bf16
{
  __shared__ unsigned short Ks[2][64 * 64];  // [s][64 d] swizzled
  __shared__ unsigned short Vs[2][64 * 64];  // [d][64 s] swizzled
  const int tid = threadIdx.x;
  const int l = tid & 63;
  const int w = tid >> 6;
  const int lq = l & 31;                     // this lane's q row (and V^T d row)
  const int h = l >> 5;
  const int bh = blockIdx.x;
  const int qc = (T_LEN / 128 - 1) - blockIdx.y;   // tail-first dispatch
  const int b = bh >> 4, hh = bh & 15;
  const size_t tb = (size_t)bh * T_LEN;

  const int q0w = qc * 128 + w * 32;
  const int qg = q0w + lq;

  // Q B-frags: step s covers d = s*16 + h*8 .. +8
  bf16x8 qf[4];
#pragma unroll
  for (int s = 0; s < 4; ++s)
    qf[s] = *(const bf16x8*)(Qb + (tb + qg) * HD + s * 16 + h * 8);

  f32x16 acc0, acc1;
#pragma unroll
  for (int r = 0; r < 16; ++r) { acc0[r] = 0.f; acc1[r] = 0.f; }
  float mrun = -1e30f, lsum = 0.f;

  const int lrow = l >> 3;
  const int lcolb = ((l & 7) << 4) ^ (lrow << 4);  // pre-swizzled source col
  const int last = 2 * qc + 1;

  // prologue: stage tile 0 into buffer 0 (wave w stages rows [w*16, w*16+16))
#pragma unroll
  for (int c = 0; c < 2; ++c) {
    const int r0 = w * 16 + c * 8;
    const int row = r0 + lrow;
    gload16((const char*)Kb + ((tb + row) * HD) * 2 + lcolb, (char*)Ks[0] + r0 * 128);
    gload16((const char*)Vt + (((size_t)bh * HD + row) * T_LEN) * 2 + lcolb,
            (char*)Vs[0] + r0 * 128);
  }
  __syncthreads();

  for (int kbi = 0; kbi <= last; ++kbi) {
    const int s0 = kbi * 64;
    const int cur = kbi & 1;

    if (kbi < last) {
      const int sn = s0 + 64;
#pragma unroll
      for (int c = 0; c < 2; ++c) {
        const int r0 = w * 16 + c * 8;
        const int row = r0 + lrow;
        gload16((const char*)Kb + ((tb + sn + row) * HD) * 2 + lcolb,
                (char*)Ks[cur ^ 1] + r0 * 128);
        gload16((const char*)Vt + (((size_t)bh * HD + row) * T_LEN + sn) * 2 + lcolb,
                (char*)Vs[cur ^ 1] + r0 * 128);
      }
    }

    const int dmax = q0w + 31 - s0;
    if (dmax >= 0) {
      const char* Kc = (const char*)Ks[cur];
      const char* Vc = (const char*)Vs[cur];
      const bool st1 = (dmax >= 32);
      const bool maskN = (s0 + 63 > q0w);

      // S^T = mfma(K, Q): D[row=s][col=q]; lane holds s = (r&3)+8*(r>>2)+4h (+st*32), q = lq
      f32x16 sv0, sv1;
#pragma unroll
      for (int r = 0; r < 16; ++r) { sv0[r] = -1e30f; sv1[r] = -1e30f; }
      {
        f32x16 z;
#pragma unroll
        for (int r = 0; r < 16; ++r) z[r] = 0.f;
        const int krow = lq;                   // st=0
        const int kswz = (krow & 7) << 4;
#pragma unroll
        for (int s = 0; s < 4; ++s) {
          bf16x8 ka = *(const bf16x8*)(Kc + krow * 128 + ((s * 32 + h * 16) ^ kswz));
          z = __builtin_amdgcn_mfma_f32_32x32x16_bf16(ka, qf[s], z, 0, 0, 0);
        }
        sv0 = z;
      }
      if (st1) {
        f32x16 z;
#pragma unroll
        for (int r = 0; r < 16; ++r) z[r] = 0.f;
        const int krow = 32 + lq;              // st=1
        const int kswz = (krow & 7) << 4;
#pragma unroll
        for (int s = 0; s < 4; ++s) {
          bf16x8 ka = *(const bf16x8*)(Kc + krow * 128 + ((s * 32 + h * 16) ^ kswz));
          z = __builtin_amdgcn_mfma_f32_32x32x16_bf16(ka, qf[s], z, 0, 0, 0);
        }
        sv1 = z;
      }

      if (maskN) {
#pragma unroll
        for (int r = 0; r < 16; ++r) {
          const int sl = (r & 3) + 8 * (r >> 2) + 4 * h;
          if (s0 + sl > qg)      sv0[r] = -1e30f;
          if (s0 + 32 + sl > qg) sv1[r] = -1e30f;
        }
      }

      // online softmax: per-lane q; merge halves with one shfl_xor(32)
      float tmax = -1e30f;
#pragma unroll
      for (int r = 0; r < 16; ++r) tmax = fmaxf(tmax, fmaxf(sv0[r], sv1[r]));
      tmax = fmaxf(tmax, __shfl_xor(tmax, 32));
      const float mnew = fmaxf(mrun, tmax);
      const float alpha = exp2f(mrun - mnew);
      float ps = 0.f;
#pragma unroll
      for (int r = 0; r < 16; ++r) { sv0[r] = exp2f(sv0[r] - mnew); ps += sv0[r]; }
      if (st1) {
#pragma unroll
        for (int r = 0; r < 16; ++r) { sv1[r] = exp2f(sv1[r] - mnew); ps += sv1[r]; }
      }
      ps += __shfl_xor(ps, 32);
      lsum = lsum * alpha + ps;
      mrun = mnew;
#pragma unroll
      for (int r = 0; r < 16; ++r) { acc0[r] *= alpha; acc1[r] *= alpha; }

      // P^T -> bf16 B-frags: 16 cvt_pk + 8 permlane32_swap per tile
      // u[a][j] covers s_local = 8a + 4h + 2j + {0,1}
      unsigned int u0[4][2], u1[4][2];
#pragma unroll
      for (int a = 0; a < 4; ++a) {
        asm("v_cvt_pk_bf16_f32 %0, %1, %2" : "=v"(u0[a][0]) : "v"(sv0[4*a]),   "v"(sv0[4*a+1]));
        asm("v_cvt_pk_bf16_f32 %0, %1, %2" : "=v"(u0[a][1]) : "v"(sv0[4*a+2]), "v"(sv0[4*a+3]));
      }
      if (st1) {
#pragma unroll
        for (int a = 0; a < 4; ++a) {
          asm("v_cvt_pk_bf16_f32 %0, %1, %2" : "=v"(u1[a][0]) : "v"(sv1[4*a]),   "v"(sv1[4*a+1]));
          asm("v_cvt_pk_bf16_f32 %0, %1, %2" : "=v"(u1[a][1]) : "v"(sv1[4*a+2]), "v"(sv1[4*a+3]));
        }
      }

      // ctx^T = mfma(V^T, P^T): A = V^T[d=dt*32+lq][s chunk], B = P^T frag
      const int vswz0 = (lq & 7) << 4;
#pragma unroll
      for (int st = 0; st < 2; ++st) {
        if (st == 1 && !st1) break;
#pragma unroll
        for (int cc = 0; cc < 2; ++cc) {
          unsigned int x0 = st ? u1[2*cc][0] : u0[2*cc][0];
          unsigned int y0 = st ? u1[2*cc+1][0] : u0[2*cc+1][0];
          unsigned int x1 = st ? u1[2*cc][1] : u0[2*cc][1];
          unsigned int y1 = st ? u1[2*cc+1][1] : u0[2*cc+1][1];
          asm("v_permlane32_swap_b32 %0, %1" : "+v"(x0), "+v"(y0));
          asm("v_permlane32_swap_b32 %0, %1" : "+v"(x1), "+v"(y1));
          U8 pf;
          pf.u[0] = x0; pf.u[1] = x1; pf.u[2] = y0; pf.u[3] = y1;
          const int soff = st * 64 + cc * 32 + h * 16;   // bytes within V^T row
          {
            bf16x8 va = *(const bf16x8*)(Vc + lq * 128 + (soff ^ vswz0));
            acc0 = __builtin_amdgcn_mfma_f32_32x32x16_bf16(va, pf.v, acc0, 0, 0, 0);
          }
          {
            const int row = 32 + lq;
            bf16x8 va = *(const bf16x8*)(Vc + row * 128 + (soff ^ ((row & 7) << 4)));
            acc1 = __builtin_amdgcn_mfma_f32_32x32x16_bf16(va, pf.v, acc1, 0, 0, 0);
          }
        }
      }
    }

    __syncthreads();   // reads of buf[cur] done AND next tile's DMA drained
  }

  // epilogue: lane holds ctx^T[d][q=lq]; d = dt*32 + 8g + 4h + j (j=0..3 consecutive)
  const float linv = 1.f / lsum;
  unsigned short* orow = ctx + ((size_t)qg * B_SZ + b) * D_MODEL + hh * HD;
#pragma unroll
  for (int g = 0; g < 4; ++g) {
    u16x4 o0, o1;
#pragma unroll
    for (int j = 0; j < 4; ++j) {
      o0[j] = f2bf(acc0[4*g + j] * linv);
      o1[j] = f2bf(acc1[4*g + j] * linv);
    }
    *(u16x4*)(orow + 8*g + 4*h)      = o0;
    *(u16x4*)(orow + 32 + 8*g + 4*h) = o1;
  }
}

extern "C" void kernel_launch(void* const* d_in, const int* in_sizes, int n_in,
                              void* d_out, int out_size, void* d_ws, size_t ws_size,
                              hipStream_t stream) {
  const float* x    = (const float*)d_in[0];
  const float* Wqkv = (const float*)d_in[2];
  const float* bqkv = (const float*)d_in[3];
  const float* Wout = (const float*)d_in[4];
  const float* bout = (const float*)d_in[5];
  float* out = (float*)d_out;

  char* wsb = (char*)d_ws;
  unsigned short* xb    = (unsigned short*)(wsb);                  // 16 MiB
  unsigned short* wqkvb = (unsigned short*)(wsb + (16ull << 20));  // 6 MiB
  unsigned short* woutb = (unsigned short*)(wsb + (22ull << 20));  // 2 MiB
  unsigned short* qb    = (unsigned short*)(wsb + (24ull << 20));  // 16 MiB
  unsigned short* kb    = (unsigned short*)(wsb + (40ull << 20));  // 16 MiB
  unsigned short* vt    = (unsigned short*)(wsb + (56ull << 20));  // 16 MiB (transposed V)
  unsigned short* ctxb  = (unsigned short*)(wsb + (72ull << 20));  // 16 MiB

  cvt_bf16_kernel<<<(T_LEN*B_SZ*D_MODEL/8 + 255)/256, 256, 0, stream>>>(x, xb, T_LEN*B_SZ*D_MODEL/8);
  cvt_bf16_kernel<<<(3*D_MODEL*D_MODEL/8 + 255)/256, 256, 0, stream>>>(Wqkv, wqkvb, 3*D_MODEL*D_MODEL/8);
  cvt_bf16_kernel<<<(D_MODEL*D_MODEL/8 + 255)/256, 256, 0, stream>>>(Wout, woutb, D_MODEL*D_MODEL/8);

  dim3 g1(3 * D_MODEL / 128, (T_LEN * B_SZ) / 128);
  gemm_mfma_kernel<<<g1, 256, 0, stream>>>(xb, wqkvb, bqkv, nullptr,
                                           T_LEN * B_SZ, 3 * D_MODEL, D_MODEL, 1,
                                           qb, kb, vt);
  const int rope_total = BH_TOT * T_LEN * (HD / 2);
  rope_bf16_kernel<<<(rope_total + 255) / 256, 256, 0, stream>>>(qb, kb);

  dim3 g2(BH_TOT, T_LEN / 128);
  attn_mfma_kernel<<<g2, 256, 0, stream>>>(qb, kb, vt, ctxb);

  dim3 g3(D_MODEL / 128, (T_LEN * B_SZ) / 128);
  gemm_mfma_kernel<<<g3, 256, 0, stream>>>(ctxb, woutb, bout, out,
                                           T_LEN * B_SZ, D_MODEL, D_MODEL, 0,
                                           nullptr, nullptr, nullptr);
}

// Round 6
// 220.305 us; speedup vs baseline: 1.1196x; 1.0204x over previous
//
#include <hip/hip_runtime.h>
#include <math.h>

#define T_LEN 2048
#define B_SZ 4
#define D_MODEL 1024
#define NH 16
#define HD 64
#define BH_TOT (B_SZ*NH)

typedef __attribute__((ext_vector_type(8))) short bf16x8;
typedef __attribute__((ext_vector_type(4))) float f32x4;
typedef __attribute__((ext_vector_type(16))) float f32x16;
typedef __attribute__((ext_vector_type(8))) unsigned short u16x8;
typedef __attribute__((ext_vector_type(4))) unsigned short u16x4;

union U8 { unsigned int u[4]; bf16x8 v; };

static __device__ __forceinline__ unsigned short f2bf(float f) {
  unsigned int x = __float_as_uint(f);
  x += 0x7fffu + ((x >> 16) & 1u);
  return (unsigned short)(x >> 16);
}
static __device__ __forceinline__ float bf2f(unsigned short u) {
  return __uint_as_float(((unsigned int)u) << 16);
}
// async global->LDS DMA, 16B per lane; LDS dest = wave-uniform base + lane*16
static __device__ __forceinline__ void gload16(const void* g, void* l) {
  __builtin_amdgcn_global_load_lds((const __attribute__((address_space(1))) void*)g,
                                   (__attribute__((address_space(3))) void*)l, 16, 0, 0);
}

// ---------------- fused fp32 -> bf16 convert of x, W_qkv, W_out ----------------
__global__ __launch_bounds__(256) void cvt3_kernel(
    const float* __restrict__ x, const float* __restrict__ wq, const float* __restrict__ wo,
    unsigned short* __restrict__ xb, unsigned short* __restrict__ wqb,
    unsigned short* __restrict__ wob) {
  const int i = blockIdx.x * 256 + threadIdx.x;
  const int N1 = T_LEN * B_SZ * D_MODEL / 8;
  const int N2 = N1 + 3 * D_MODEL * D_MODEL / 8;
  const int N3 = N2 + D_MODEL * D_MODEL / 8;
  const float* s; unsigned short* d; int off;
  if (i < N1)      { s = x;  d = xb;  off = i; }
  else if (i < N2) { s = wq; d = wqb; off = i - N1; }
  else if (i < N3) { s = wo; d = wob; off = i - N2; }
  else return;
  const float4 a = ((const float4*)s)[off * 2];
  const float4 b = ((const float4*)s)[off * 2 + 1];
  u16x8 o;
  o[0] = f2bf(a.x); o[1] = f2bf(a.y); o[2] = f2bf(a.z); o[3] = f2bf(a.w);
  o[4] = f2bf(b.x); o[5] = f2bf(b.y); o[6] = f2bf(b.z); o[7] = f2bf(b.w);
  ((u16x8*)d)[off] = o;
}

// ---------------- bf16 MFMA GEMM: C = A(MxK) * W(NxK)^T + bias ----------------
// 128x128 tile, BK=64, 4 waves (2x2). 2-phase double-buffered global_load_lds
// staging (stage k+1 while computing k; ONE barrier per K-step).
// XCD-chunked bijective block swizzle (requires grid size % 8 == 0).
// mode 0: fp32 C[m*N+n]
// mode 1: bf16 scatter q,k -> [bh][t][hd]; v -> TRANSPOSED [bh][hd][t]
__global__ __launch_bounds__(256, 2) void gemm_mfma_kernel(
    const unsigned short* __restrict__ A, const unsigned short* __restrict__ W,
    const float* __restrict__ bias, float* __restrict__ C,
    int M, int N, int K, int mode,
    unsigned short* __restrict__ qd, unsigned short* __restrict__ kd,
    unsigned short* __restrict__ vtd)
{
  __shared__ unsigned short As[2][128 * 64];   // [buf][row][64 bf16]
  __shared__ unsigned short Bs[2][128 * 64];
  const int tid = threadIdx.x;
  const int l = tid & 63, w = tid >> 6;
  const int lq = l & 15, lg = l >> 4;
  const int wm = w >> 1, wn = w & 1;

  // XCD-chunked swizzle (bijective: nwg % 8 == 0)
  const int nbx = gridDim.x;
  const int nwg = nbx * gridDim.y;
  const int flat = blockIdx.y * nbx + blockIdx.x;
  const int cpx = nwg >> 3;
  const int swz = (flat & 7) * cpx + (flat >> 3);
  const int n0 = (swz % nbx) * 128, m0 = (swz / nbx) * 128;

  const int lrow = l >> 3;
  const int lcolb = ((l & 7) << 4) ^ (lrow << 4);   // pre-swizzled source col

  f32x4 acc[4][4];
#pragma unroll
  for (int mt = 0; mt < 4; ++mt)
#pragma unroll
    for (int nt = 0; nt < 4; ++nt)
#pragma unroll
      for (int r2 = 0; r2 < 4; ++r2) acc[mt][nt][r2] = 0.f;

  const int nk = K >> 6;
  // prologue: stage K-tile 0 into buffer 0
#pragma unroll
  for (int c = 0; c < 4; ++c) {
    const int r0 = w * 32 + c * 8;
    const int row = r0 + lrow;
    gload16((const char*)A + ((size_t)(m0 + row) * K) * 2 + lcolb, (char*)As[0] + r0 * 128);
    gload16((const char*)W + ((size_t)(n0 + row) * K) * 2 + lcolb, (char*)Bs[0] + r0 * 128);
  }
  __syncthreads();                              // vmcnt drained, tile 0 ready

  for (int kt = 0; kt < nk; ++kt) {
    const int cur = kt & 1;
    if (kt + 1 < nk) {                          // issue next tile's DMA now
      const int k1 = (kt + 1) << 6;
#pragma unroll
      for (int c = 0; c < 4; ++c) {
        const int r0 = w * 32 + c * 8;
        const int row = r0 + lrow;
        gload16((const char*)A + ((size_t)(m0 + row) * K + k1) * 2 + lcolb,
                (char*)As[cur ^ 1] + r0 * 128);
        gload16((const char*)W + ((size_t)(n0 + row) * K + k1) * 2 + lcolb,
                (char*)Bs[cur ^ 1] + r0 * 128);
      }
    }

#pragma unroll
    for (int kc = 0; kc < 2; ++kc) {
      bf16x8 af[4], bfr[4];
#pragma unroll
      for (int mt = 0; mt < 4; ++mt) {
        const int r = wm * 64 + mt * 16 + lq;
        af[mt] = *(const bf16x8*)((const char*)As[cur] + r * 128 +
                                  ((kc * 64 + lg * 16) ^ ((r & 7) << 4)));
      }
#pragma unroll
      for (int nt = 0; nt < 4; ++nt) {
        const int r = wn * 64 + nt * 16 + lq;
        bfr[nt] = *(const bf16x8*)((const char*)Bs[cur] + r * 128 +
                                   ((kc * 64 + lg * 16) ^ ((r & 7) << 4)));
      }
#pragma unroll
      for (int mt = 0; mt < 4; ++mt)
#pragma unroll
        for (int nt = 0; nt < 4; ++nt)
          acc[mt][nt] = __builtin_amdgcn_mfma_f32_16x16x32_bf16(af[mt], bfr[nt], acc[mt][nt], 0, 0, 0);
    }
    __syncthreads();    // reads of buf[cur] done AND next tile's DMA drained
  }

  if (mode == 0) {
#pragma unroll
    for (int nt = 0; nt < 4; ++nt) {
      const int n = n0 + wn * 64 + nt * 16 + lq;
      const float bv = bias[n];
#pragma unroll
      for (int mt = 0; mt < 4; ++mt)
#pragma unroll
        for (int r2 = 0; r2 < 4; ++r2) {
          const int m = m0 + wm * 64 + mt * 16 + lg * 4 + r2;
          C[(size_t)m * N + n] = acc[mt][nt][r2] + bv;
        }
    }
  } else {
#pragma unroll
    for (int nt = 0; nt < 4; ++nt) {
      const int n = n0 + wn * 64 + nt * 16 + lq;
      const float bv = bias[n];
      const int which = n >> 10;
      const int h = (n >> 6) & (NH - 1);
      const int hd = n & 63;
#pragma unroll
      for (int mt = 0; mt < 4; ++mt)
#pragma unroll
        for (int r2 = 0; r2 < 4; ++r2) {
          const int m = m0 + wm * 64 + mt * 16 + lg * 4 + r2;
          const int t = m >> 2, b = m & 3;
          const unsigned short val = f2bf(acc[mt][nt][r2] + bv);
          if (which == 2) {
            vtd[((size_t)(b * NH + h) * HD + hd) * T_LEN + t] = val;   // V transposed
          } else {
            unsigned short* dst = (which == 0) ? qd : kd;
            dst[((size_t)(b * NH + h) * T_LEN + t) * HD + hd] = val;
          }
        }
    }
  }
}

// ---------------- RoPE in place; q pre-scaled by log2(e)/8 (exp2-domain softmax) ----------------
__global__ void rope_bf16_kernel(unsigned short* __restrict__ qb, unsigned short* __restrict__ kb)
{
  const int idx = blockIdx.x * blockDim.x + threadIdx.x;
  const int i  = idx & 31;
  const int t  = (idx >> 5) & (T_LEN - 1);
  const int bh = idx >> 16;
  const float inv_freq = powf(10000.f, -(float)i / 32.f);
  float s, c;
  sincosf((float)t * inv_freq, &s, &c);
  const size_t base = ((size_t)bh * T_LEN + t) * HD;
  const float QS = 0.18033688011112042f;   // (1/8) * log2(e)
  const float q1 = bf2f(qb[base + i]), q2 = bf2f(qb[base + i + 32]);
  qb[base + i]      = f2bf((q1 * c - q2 * s) * QS);
  qb[base + i + 32] = f2bf((q2 * c + q1 * s) * QS);
  const float k1 = bf2f(kb[base + i]), k2 = bf2f(kb[base + i + 32]);
  kb[base + i]      = f2bf(k1 * c - k2 * s);
  kb[base + i + 32] = f2bf(k2 * c + k1 * s);
}

// ---------------- bf16 32x32-MFMA flash attention, fully swapped orientation ----------------
__global__ __launch_bounds__(256, 3) void attn_mfma_kernel(
    const unsigned short* __restrict__ Qb,   // [bh][t][64] bf16, pre-scaled log2e/8
    const unsigned short* __restrict__ Kb,   // [bh][t][64] bf16
    const unsigned short* __restrict__ Vt,   // [bh][64][2048] bf16 (transposed)
    unsigned short* __restrict__ ctx)        // (T, B, D) bf16
{
  __shared__ unsigned short Ks[2][64 * 64];  // [s][64 d] swizzled
  __shared__ unsigned short Vs[2][64 * 64];  // [d][64 s] swizzled
  const int tid = threadIdx.x;
  const int l = tid & 63;
  const int w = tid >> 6;
  const int lq = l & 31;                     // this lane's q row (and V^T d row)
  const int h = l >> 5;
  const int bh = blockIdx.x;
  const int qc = (T_LEN / 128 - 1) - blockIdx.y;   // tail-first dispatch
  const int b = bh >> 4, hh = bh & 15;
  const size_t tb = (size_t)bh * T_LEN;

  const int q0w = qc * 128 + w * 32;
  const int qg = q0w + lq;

  bf16x8 qf[4];
#pragma unroll
  for (int s = 0; s < 4; ++s)
    qf[s] = *(const bf16x8*)(Qb + (tb + qg) * HD + s * 16 + h * 8);

  f32x16 acc0, acc1;
#pragma unroll
  for (int r = 0; r < 16; ++r) { acc0[r] = 0.f; acc1[r] = 0.f; }
  float mrun = -1e30f, lsum = 0.f;

  const int lrow = l >> 3;
  const int lcolb = ((l & 7) << 4) ^ (lrow << 4);  // pre-swizzled source col
  const int last = 2 * qc + 1;

#pragma unroll
  for (int c = 0; c < 2; ++c) {
    const int r0 = w * 16 + c * 8;
    const int row = r0 + lrow;
    gload16((const char*)Kb + ((tb + row) * HD) * 2 + lcolb, (char*)Ks[0] + r0 * 128);
    gload16((const char*)Vt + (((size_t)bh * HD + row) * T_LEN) * 2 + lcolb,
            (char*)Vs[0] + r0 * 128);
  }
  __syncthreads();

  for (int kbi = 0; kbi <= last; ++kbi) {
    const int s0 = kbi * 64;
    const int cur = kbi & 1;

    if (kbi < last) {
      const int sn = s0 + 64;
#pragma unroll
      for (int c = 0; c < 2; ++c) {
        const int r0 = w * 16 + c * 8;
        const int row = r0 + lrow;
        gload16((const char*)Kb + ((tb + sn + row) * HD) * 2 + lcolb,
                (char*)Ks[cur ^ 1] + r0 * 128);
        gload16((const char*)Vt + (((size_t)bh * HD + row) * T_LEN + sn) * 2 + lcolb,
                (char*)Vs[cur ^ 1] + r0 * 128);
      }
    }

    const int dmax = q0w + 31 - s0;
    if (dmax >= 0) {
      const char* Kc = (const char*)Ks[cur];
      const char* Vc = (const char*)Vs[cur];
      const bool st1 = (dmax >= 32);
      const bool maskN = (s0 + 63 > q0w);

      f32x16 sv0, sv1;
#pragma unroll
      for (int r = 0; r < 16; ++r) { sv0[r] = -1e30f; sv1[r] = -1e30f; }
      {
        f32x16 z;
#pragma unroll
        for (int r = 0; r < 16; ++r) z[r] = 0.f;
        const int krow = lq;
        const int kswz = (krow & 7) << 4;
        __builtin_amdgcn_s_setprio(1);
#pragma unroll
        for (int s = 0; s < 4; ++s) {
          bf16x8 ka = *(const bf16x8*)(Kc + krow * 128 + ((s * 32 + h * 16) ^ kswz));
          z = __builtin_amdgcn_mfma_f32_32x32x16_bf16(ka, qf[s], z, 0, 0, 0);
        }
        __builtin_amdgcn_s_setprio(0);
        sv0 = z;
      }
      if (st1) {
        f32x16 z;
#pragma unroll
        for (int r = 0; r < 16; ++r) z[r] = 0.f;
        const int krow = 32 + lq;
        const int kswz = (krow & 7) << 4;
        __builtin_amdgcn_s_setprio(1);
#pragma unroll
        for (int s = 0; s < 4; ++s) {
          bf16x8 ka = *(const bf16x8*)(Kc + krow * 128 + ((s * 32 + h * 16) ^ kswz));
          z = __builtin_amdgcn_mfma_f32_32x32x16_bf16(ka, qf[s], z, 0, 0, 0);
        }
        __builtin_amdgcn_s_setprio(0);
        sv1 = z;
      }

      if (maskN) {
#pragma unroll
        for (int r = 0; r < 16; ++r) {
          const int sl = (r & 3) + 8 * (r >> 2) + 4 * h;
          if (s0 + sl > qg)      sv0[r] = -1e30f;
          if (s0 + 32 + sl > qg) sv1[r] = -1e30f;
        }
      }

      float tmax = -1e30f;
#pragma unroll
      for (int r = 0; r < 16; ++r) tmax = fmaxf(tmax, fmaxf(sv0[r], sv1[r]));
      tmax = fmaxf(tmax, __shfl_xor(tmax, 32));
      const float mnew = fmaxf(mrun, tmax);
      const float alpha = exp2f(mrun - mnew);
      float ps = 0.f;
#pragma unroll
      for (int r = 0; r < 16; ++r) { sv0[r] = exp2f(sv0[r] - mnew); ps += sv0[r]; }
      if (st1) {
#pragma unroll
        for (int r = 0; r < 16; ++r) { sv1[r] = exp2f(sv1[r] - mnew); ps += sv1[r]; }
      }
      ps += __shfl_xor(ps, 32);
      lsum = lsum * alpha + ps;
      mrun = mnew;
#pragma unroll
      for (int r = 0; r < 16; ++r) { acc0[r] *= alpha; acc1[r] *= alpha; }

      unsigned int u0[4][2], u1[4][2];
#pragma unroll
      for (int a = 0; a < 4; ++a) {
        asm("v_cvt_pk_bf16_f32 %0, %1, %2" : "=v"(u0[a][0]) : "v"(sv0[4*a]),   "v"(sv0[4*a+1]));
        asm("v_cvt_pk_bf16_f32 %0, %1, %2" : "=v"(u0[a][1]) : "v"(sv0[4*a+2]), "v"(sv0[4*a+3]));
      }
      if (st1) {
#pragma unroll
        for (int a = 0; a < 4; ++a) {
          asm("v_cvt_pk_bf16_f32 %0, %1, %2" : "=v"(u1[a][0]) : "v"(sv1[4*a]),   "v"(sv1[4*a+1]));
          asm("v_cvt_pk_bf16_f32 %0, %1, %2" : "=v"(u1[a][1]) : "v"(sv1[4*a+2]), "v"(sv1[4*a+3]));
        }
      }

      const int vswz0 = (lq & 7) << 4;
#pragma unroll
      for (int st = 0; st < 2; ++st) {
        if (st == 1 && !st1) break;
#pragma unroll
        for (int cc = 0; cc < 2; ++cc) {
          unsigned int x0 = st ? u1[2*cc][0] : u0[2*cc][0];
          unsigned int y0 = st ? u1[2*cc+1][0] : u0[2*cc+1][0];
          unsigned int x1 = st ? u1[2*cc][1] : u0[2*cc][1];
          unsigned int y1 = st ? u1[2*cc+1][1] : u0[2*cc+1][1];
          asm("v_permlane32_swap_b32 %0, %1" : "+v"(x0), "+v"(y0));
          asm("v_permlane32_swap_b32 %0, %1" : "+v"(x1), "+v"(y1));
          U8 pf;
          pf.u[0] = x0; pf.u[1] = x1; pf.u[2] = y0; pf.u[3] = y1;
          const int soff = st * 64 + cc * 32 + h * 16;
          __builtin_amdgcn_s_setprio(1);
          {
            bf16x8 va = *(const bf16x8*)(Vc + lq * 128 + (soff ^ vswz0));
            acc0 = __builtin_amdgcn_mfma_f32_32x32x16_bf16(va, pf.v, acc0, 0, 0, 0);
          }
          {
            const int row = 32 + lq;
            bf16x8 va = *(const bf16x8*)(Vc + row * 128 + (soff ^ ((row & 7) << 4)));
            acc1 = __builtin_amdgcn_mfma_f32_32x32x16_bf16(va, pf.v, acc1, 0, 0, 0);
          }
          __builtin_amdgcn_s_setprio(0);
        }
      }
    }

    __syncthreads();
  }

  const float linv = 1.f / lsum;
  unsigned short* orow = ctx + ((size_t)qg * B_SZ + b) * D_MODEL + hh * HD;
#pragma unroll
  for (int g = 0; g < 4; ++g) {
    u16x4 o0, o1;
#pragma unroll
    for (int j = 0; j < 4; ++j) {
      o0[j] = f2bf(acc0[4*g + j] * linv);
      o1[j] = f2bf(acc1[4*g + j] * linv);
    }
    *(u16x4*)(orow + 8*g + 4*h)      = o0;
    *(u16x4*)(orow + 32 + 8*g + 4*h) = o1;
  }
}

extern "C" void kernel_launch(void* const* d_in, const int* in_sizes, int n_in,
                              void* d_out, int out_size, void* d_ws, size_t ws_size,
                              hipStream_t stream) {
  const float* x    = (const float*)d_in[0];
  const float* Wqkv = (const float*)d_in[2];
  const float* bqkv = (const float*)d_in[3];
  const float* Wout = (const float*)d_in[4];
  const float* bout = (const float*)d_in[5];
  float* out = (float*)d_out;

  char* wsb = (char*)d_ws;
  unsigned short* xb    = (unsigned short*)(wsb);                  // 16 MiB
  unsigned short* wqkvb = (unsigned short*)(wsb + (16ull << 20));  // 6 MiB
  unsigned short* woutb = (unsigned short*)(wsb + (22ull << 20));  // 2 MiB
  unsigned short* qb    = (unsigned short*)(wsb + (24ull << 20));  // 16 MiB
  unsigned short* kb    = (unsigned short*)(wsb + (40ull << 20));  // 16 MiB
  unsigned short* vt    = (unsigned short*)(wsb + (56ull << 20));  // 16 MiB (transposed V)
  unsigned short* ctxb  = (unsigned short*)(wsb + (72ull << 20));  // 16 MiB

  const int ncvt = T_LEN*B_SZ*D_MODEL/8 + 3*D_MODEL*D_MODEL/8 + D_MODEL*D_MODEL/8;
  cvt3_kernel<<<(ncvt + 255)/256, 256, 0, stream>>>(x, Wqkv, Wout, xb, wqkvb, woutb);

  dim3 g1(3 * D_MODEL / 128, (T_LEN * B_SZ) / 128);
  gemm_mfma_kernel<<<g1, 256, 0, stream>>>(xb, wqkvb, bqkv, nullptr,
                                           T_LEN * B_SZ, 3 * D_MODEL, D_MODEL, 1,
                                           qb, kb, vt);
  const int rope_total = BH_TOT * T_LEN * (HD / 2);
  rope_bf16_kernel<<<(rope_total + 255) / 256, 256, 0, stream>>>(qb, kb);

  dim3 g2(BH_TOT, T_LEN / 128);
  attn_mfma_kernel<<<g2, 256, 0, stream>>>(qb, kb, vt, ctxb);

  dim3 g3(D_MODEL / 128, (T_LEN * B_SZ) / 128);
  gemm_mfma_kernel<<<g3, 256, 0, stream>>>(ctxb, woutb, bout, out,
                                           T_LEN * B_SZ, D_MODEL, D_MODEL, 0,
                                           nullptr, nullptr, nullptr);
}